// Round 15
// baseline (147.280 us; speedup 1.0000x reference)
//
#include <hip/hip_runtime.h>
#include <math.h>

#define N_G   64
#define M_N   32
#define FEAT  256
#define POSD  6
#define D     262
#define MSG   128
#define NCLS  7

#define KA_S  424       // LDS buf row stride (shorts): [mv 128 | h 262 | pad]
#define PSTR  320       // paL/pbL row stride (shorts)

// ---------------------------------------------------------------------------
// COALESCED tile-major weight layout (R11). Slab = 512 shorts (64 lanes x 8).
// Chunk (tile s, k-step kk, lane) contiguous -> each wave weight load is one
// 1KB fully-coalesced transaction. Region slab counts:
//   proj 33x9 | msg 8x9 | rz 2x17x13 | xn 17x4 | hn 17x9 | ro 8x9 | ro2 1x4
// NOTE (R13 lesson): this kernel is ~20 VGPR from the spill cliff. Do NOT
// unroll the GRU s-loop or select across pinned arrays. The R15 tail below
// uses per-branch macro instantiation (static indexing, no select, no unroll).
// ---------------------------------------------------------------------------
#define O_WPROJ 0u
#define O_WMSG  76032u
#define O_WRZ   94464u
#define O_WXN   207616u
#define O_WHN   225024u
#define O_WRO   264192u
#define O_WRO2  282624u
#define O_GB    283648u   // 1088 fp32 gate biases [br|bz|bxn|bhn] x 272

typedef __attribute__((ext_vector_type(8))) short short8;
typedef __attribute__((ext_vector_type(4))) short short4v;
typedef __attribute__((ext_vector_type(4))) float floatx4;

#define MFMA __builtin_amdgcn_mfma_f32_16x16x32_bf16

__device__ __forceinline__ short f2bf(float f) {
    union { float f; unsigned u; } v; v.f = f;
    unsigned r = v.u + 0x7FFF + ((v.u >> 16) & 1);   // RNE
    return (short)(r >> 16);
}
__device__ __forceinline__ float bf2f(short s) {
    union { float f; unsigned u; } v;
    v.u = ((unsigned)(unsigned short)s) << 16;
    return v.f;
}
// fast sigmoid/tanh: v_exp_f32 + v_rcp_f32 (~1e-6 rel err, vs bf16-path 5e-3)
__device__ __forceinline__ float sigf(float x) {
    return __builtin_amdgcn_rcpf(1.f + __expf(-x));
}
__device__ __forceinline__ float tanh_fast(float x) {
    float e = __expf(-2.f * fabsf(x));
    float t = (1.f - e) * __builtin_amdgcn_rcpf(1.f + e);
    return copysignf(t, x);
}

// ---------------------------------------------------------------------------
// prep: SLAB-PER-WAVE pack into the coalesced tile-major layout (R11).
// ---------------------------------------------------------------------------
__global__ __launch_bounds__(256) void prep_kernel(
    const float* __restrict__ w1, const float* __restrict__ msg_w,
    const float* __restrict__ w_ih, const float* __restrict__ w_hh,
    const float* __restrict__ ro_w1, const float* __restrict__ ro_w2,
    const float* __restrict__ b_ih, const float* __restrict__ b_hh,
    float* __restrict__ ws)
{
    short* wproj = (short*)(ws + O_WPROJ);
    short* wmsg  = (short*)(ws + O_WMSG);
    short* wrz   = (short*)(ws + O_WRZ);
    short* wxn   = (short*)(ws + O_WXN);
    short* whn   = (short*)(ws + O_WHN);
    short* wro   = (short*)(ws + O_WRO);
    short* wro2  = (short*)(ws + O_WRO2);
    float* gb    = ws + O_GB;

    int job = blockIdx.x * 4 + (threadIdx.x >> 6);
    const int lane = threadIdx.x & 63;
    if (job >= 1112) return;
    const int lrow = lane & 15, quad = lane >> 4;

    if (job < 297) {                              // proj: s 0..32, kk 0..8
        const int s = job / 9, kk = job % 9;
        const int n = s * 16 + lrow, kb = quad * 8 + kk * 32;
        short8 o;
#pragma unroll
        for (int e = 0; e < 8; ++e) {
            int k = kb + e;
            float v = 0.f;
            if (k < D && n < 524)
                v = (n < D) ? w1[n * 524 + k] : w1[(n - D) * 524 + D + k];
            o[e] = f2bf(v);
        }
        *(short8*)(wproj + job * 512 + lane * 8) = o;
        return;
    }
    job -= 297;
    if (job < 72) {                               // msg: s 0..7, kk 0..8
        const int s = job / 9, kk = job % 9;
        const int n = s * 16 + lrow, kb = quad * 8 + kk * 32;
        short8 o;
#pragma unroll
        for (int e = 0; e < 8; ++e) {
            int k = kb + e;
            o[e] = f2bf(k < D ? msg_w[n * D + k] : 0.f);
        }
        *(short8*)(wmsg + job * 512 + lane * 8) = o;
        return;
    }
    job -= 72;
    if (job < 442) {                              // rz: [r slabs 0..220][z 221..441]
        const int gi = job >= 221;
        const int jj = job - gi * 221;
        const int s = jj / 13, kk = jj % 13;
        const int d = s * 16 + lrow, kb = quad * 8 + kk * 32;
        short8 o;
#pragma unroll
        for (int e = 0; e < 8; ++e) {
            int k = kb + e;
            float v = 0.f;
            if (d < D) {
                int r = gi * D + d;
                if (k < 128)          v = w_ih[r * MSG + k];
                else if (k < 128 + D) v = w_hh[r * D + (k - 128)];
            }
            o[e] = f2bf(v);
        }
        *(short8*)(wrz + job * 512 + lane * 8) = o;
        return;
    }
    job -= 442;
    if (job < 68) {                               // xn: s 0..16, kk 0..3
        const int s = job / 4, kk = job % 4;
        const int d = s * 16 + lrow, kb = quad * 8 + kk * 32;
        short8 o;
#pragma unroll
        for (int e = 0; e < 8; ++e) {
            int k = kb + e;
            o[e] = f2bf(d < D ? w_ih[(2 * D + d) * MSG + k] : 0.f);
        }
        *(short8*)(wxn + job * 512 + lane * 8) = o;
        return;
    }
    job -= 68;
    if (job < 153) {                              // hn: s 0..16, kk 0..8
        const int s = job / 9, kk = job % 9;
        const int d = s * 16 + lrow, kb = quad * 8 + kk * 32;
        short8 o;
#pragma unroll
        for (int e = 0; e < 8; ++e) {
            int k = kb + e;
            o[e] = f2bf((d < D && k < D) ? w_hh[(2 * D + d) * D + k] : 0.f);
        }
        *(short8*)(whn + job * 512 + lane * 8) = o;
        return;
    }
    job -= 153;
    if (job < 72) {                               // ro: s 0..7, kk 0..8
        const int s = job / 9, kk = job % 9;
        const int n = s * 16 + lrow, kb = quad * 8 + kk * 32;
        short8 o;
#pragma unroll
        for (int e = 0; e < 8; ++e) {
            int k = kb + e;
            o[e] = f2bf(k < D ? ro_w1[n * D + k] : 0.f);
        }
        *(short8*)(wro + job * 512 + lane * 8) = o;
        return;
    }
    job -= 72;
    if (job < 4) {                                // ro2: kk 0..3
        const int kk = job;
        const int n = lrow, kb = quad * 8 + kk * 32;
        short8 o;
#pragma unroll
        for (int e = 0; e < 8; ++e) {
            int k = kb + e;
            o[e] = f2bf(n < NCLS ? ro_w2[n * MSG + k] : 0.f);
        }
        *(short8*)(wro2 + job * 512 + lane * 8) = o;
        return;
    }
    job -= 4;
    {                                             // gate biases [4][272]
        const int seg = job;
        float* out = gb + seg * 272;
        for (int d = lane; d < 272; d += 64) {
            float v = 0.f;
            if (d < D) {
                if (seg == 0)      v = b_ih[d] + b_hh[d];
                else if (seg == 1) v = b_ih[D + d] + b_hh[D + d];
                else if (seg == 2) v = b_ih[2 * D + d];
                else               v = b_hh[2 * D + d];
            }
            out[d] = v;
        }
    }
}

// ---------------------------------------------------------------------------
// fused: one block per graph; R15 = R14 (best: 49.5us fused) + GRU barrier
// balance. Main GRU loop now covers tiles 0..15 (exactly 2/wave); tile 16
// runs as m-halves on waves 0/1 via per-branch macro instantiation (static
// indexing, no cross-array select, no unroll -> no R13 spill hazard).
// Crit path 3 tiles -> 2.5.
// ---------------------------------------------------------------------------
__global__ __launch_bounds__(512, 2) void fused_kernel(
    const float* __restrict__ nodes, const float* __restrict__ pos,
    const int* __restrict__ nrec_g,
    const float* __restrict__ b1g, const float* __restrict__ w2g,
    const float* __restrict__ b2g, const float* __restrict__ msg_bg,
    const float* __restrict__ ro_b1g, const float* __restrict__ ro_b2g,
    const float* __restrict__ ws,
    float* __restrict__ att_out, float* __restrict__ pred)
{
    const short* Wproj = (const short*)(ws + O_WPROJ);
    const short* Wmsg  = (const short*)(ws + O_WMSG);
    const short* Wrz   = (const short*)(ws + O_WRZ);
    const short* Wxn   = (const short*)(ws + O_WXN);
    const short* Whn   = (const short*)(ws + O_WHN);
    const short* Wro   = (const short*)(ws + O_WRO);
    const short* Wro2  = (const short*)(ws + O_WRO2);
    const float* gb    = ws + O_GB;

    __shared__ __align__(16) short bufA[32 * KA_S];
    __shared__ __align__(16) short bufB[32 * KA_S];
    __shared__ __align__(16) short paL[32 * PSTR];
    __shared__ __align__(16) short pbL[32 * PSTR];
    __shared__ __align__(16) short attL[32 * 40];   // bf16 A-layout for mix
    __shared__ __align__(16) short msgT[128 * 40];  // bf16 B^T layout for mix
    __shared__ __align__(16) short hidL[32 * 136];
    __shared__ __align__(16) float b1L[PSTR], w2L[PSTR];

    const int b = blockIdx.x;
    const int tid = threadIdx.x;
    const int wave = tid >> 6, lane = tid & 63;
    const int quad = lane >> 4, lrow = lane & 15;

    // ---- L2 priming: touch Wrz/Wxn/Whn (contiguous ~679 KB) early ----
    floatx4 prm[10];
    {
        const floatx4* pb = (const floatx4*)(ws + O_WRZ);
        const int base = wave * 64 + lane;
#pragma unroll
        for (int p = 0; p < 10; ++p)
            prm[p] = pb[(p * 512 + base) * 8];      // 8 floatx4 = 128 B stride
    }
    // ---- prefetch P1 tile-'wave' weights (hides under P0) ----
    short8 wvA[9];
    {
        const short* bw = Wproj + wave * 9 * 512 + lane * 8;
#pragma unroll
        for (int kk = 0; kk < 9; ++kk) wvA[kk] = *(const short8*)(bw + kk * 512);
    }

    const int nr = nrec_g[b];

    // ---- P0: load h0 bf16, zero pads, stage padded b1/w2 ----
    for (int idx = tid; idx < 32 * 64; idx += 512) {          // nodes (float4)
        int w = idx >> 6, c4 = idx & 63;
        floatx4 v = *(const floatx4*)(nodes + ((size_t)(b * 32 + w)) * FEAT + c4 * 4);
        short4v s; s[0] = f2bf(v[0]); s[1] = f2bf(v[1]); s[2] = f2bf(v[2]); s[3] = f2bf(v[3]);
        *(short4v*)(bufA + w * KA_S + 128 + c4 * 4) = s;
    }
    for (int idx = tid; idx < 32 * POSD; idx += 512) {        // pos
        int w = idx / POSD, c = idx % POSD;
        bufA[w * KA_S + 128 + FEAT + c] = f2bf(pos[((size_t)(b * 32 + w)) * POSD + c]);
    }
    for (int idx = tid; idx < 32 * 34; idx += 512) {          // col pads 390..423
        int w = idx / 34, c = idx % 34;
        bufA[w * KA_S + 390 + c] = 0;
        bufB[w * KA_S + 390 + c] = 0;
    }
    for (int idx = tid; idx < 32 * (PSTR - D); idx += 512) {  // pa/pb pads 262..319
        int w = idx / (PSTR - D), c = idx % (PSTR - D);
        paL[w * PSTR + D + c] = 0;
        pbL[w * PSTR + D + c] = 0;
    }
    for (int d = tid; d < PSTR; d += 512) {
        b1L[d] = (d < D) ? b1g[d] : 0.f;
        w2L[d] = (d < D) ? w2g[d] : 0.f;
    }
    // keep priming loads alive (and let their latency overlap P0's work)
#pragma unroll
    for (int p = 0; p < 10; ++p) asm volatile("" :: "v"(prm[p]));
    __syncthreads();

    // ---- P1: combined GEMM over h0 (tiles 0..32 proj, 33..40 round-0 msg) ----
    {
        auto store_proj = [&](int s, floatx4 acc0, floatx4 acc1) {
            int col = s * 16 + lrow;
#pragma unroll
            for (int rr = 0; rr < 4; ++rr) {
                int r0 = quad * 4 + rr;
                if (col < D) {
                    paL[r0 * PSTR + col] = f2bf(acc0[rr]);
                    paL[(r0 + 16) * PSTR + col] = f2bf(acc1[rr]);
                } else if (col < 2 * D) {
                    pbL[r0 * PSTR + (col - D)] = f2bf(acc0[rr]);
                    pbL[(r0 + 16) * PSTR + (col - D)] = f2bf(acc1[rr]);
                }
            }
        };
        auto store_msg = [&](int s, floatx4 acc0, floatx4 acc1) {
            int col = (s - 33) * 16 + lrow;
            float bias = msg_bg[col];
#pragma unroll
            for (int rr = 0; rr < 4; ++rr) {
                msgT[col * 40 + quad * 4 + rr] = f2bf(acc0[rr] + bias);
                msgT[col * 40 + 16 + quad * 4 + rr] = f2bf(acc1[rr] + bias);
            }
        };

        short8 aF0[9], aF1[9];
        {
            const short* ap = bufA + lrow * KA_S + 128 + quad * 8;
#pragma unroll
            for (int kk = 0; kk < 9; ++kk) {
                aF0[kk] = *(const short8*)(ap + kk * 32);
                aF1[kk] = *(const short8*)(ap + 16 * KA_S + kk * 32);
            }
#pragma unroll
            for (int kk = 0; kk < 9; ++kk)
                asm volatile("" : "+v"(aF0[kk]), "+v"(aF1[kk]));
        }
        short8 wvB[9];

#define P1_LOAD(DST, TT) do { \
            const short* bw_ = ((TT) < 33) \
                ? Wproj + (TT) * 9 * 512 + lane * 8 \
                : Wmsg + ((TT) - 33) * 9 * 512 + lane * 8; \
            _Pragma("unroll") \
            for (int kk = 0; kk < 9; ++kk) DST[kk] = *(const short8*)(bw_ + kk * 512); \
        } while (0)

#define P1_TILE(W, TT) do { \
            floatx4 acc0_ = {}, acc1_ = {}; \
            _Pragma("unroll") \
            for (int kk = 0; kk < 9; ++kk) { \
                acc0_ = MFMA(aF0[kk], W[kk], acc0_, 0, 0, 0); \
                acc1_ = MFMA(aF1[kk], W[kk], acc1_, 0, 0, 0); \
            } \
            if ((TT) < 33) store_proj((TT), acc0_, acc1_); \
            else store_msg((TT), acc0_, acc1_); \
        } while (0)

        int t = wave;                       // 0..7
        P1_LOAD(wvB, t + 8);                // stage next while computing current
        P1_TILE(wvA, t);
        t += 8;                             // 8..15
        P1_LOAD(wvA, t + 8);
        P1_TILE(wvB, t);
        t += 8;                             // 16..23
        P1_LOAD(wvB, t + 8);
        P1_TILE(wvA, t);
        t += 8;                             // 24..31
        P1_LOAD(wvA, t + 8);                // 32..39: always valid
        P1_TILE(wvB, t);
        t += 8;                             // 32..39
        if (t + 8 < 41) P1_LOAD(wvB, t + 8);  // only wave 0 stages tile 40
        P1_TILE(wvA, t);
        t += 8;                             // 40 for wave 0
        if (t < 41) P1_TILE(wvB, t);
#undef P1_LOAD
#undef P1_TILE
    }
    __syncthreads();

    // ---- P2: attention — 32 groups of 16 lanes, 32 j's each ----
    {
        const int grp = tid >> 4;          // i = grp (0..31)
        const int c16 = tid & 15;
        const float b2v = b2g[0];
        float pav[5][4], b1v[5][4], w2v[5][4];
#pragma unroll
        for (int k = 0; k < 5; ++k) {
            int dbase = c16 * 4 + 64 * k;
            short4v p = *(const short4v*)(paL + grp * PSTR + dbase);
            floatx4 bb = *(const floatx4*)(b1L + dbase);
            floatx4 ww = *(const floatx4*)(w2L + dbase);
#pragma unroll
            for (int e = 0; e < 4; ++e) {
                pav[k][e] = bf2f(p[e]); b1v[k][e] = bb[e]; w2v[k][e] = ww[e];
            }
        }
        // c0 = invalid-pair logit
        float p0 = 0.f;
#pragma unroll
        for (int k = 0; k < 5; ++k)
#pragma unroll
            for (int e = 0; e < 4; ++e)
                p0 += fmaxf(b1v[k][e], 0.f) * w2v[k][e];
        p0 += __shfl_down(p0, 8, 16); p0 += __shfl_down(p0, 4, 16);
        p0 += __shfl_down(p0, 2, 16); p0 += __shfl_down(p0, 1, 16);
        float c0 = sigf(p0 + b2v);
        const bool vi = grp < nr;
        for (int j = 0; j < 32; ++j) {
            float a;
            if (j < nr && vi) {
                const short* pb = pbL + j * PSTR + c16 * 4;
                float s = 0.f;
#pragma unroll
                for (int k = 0; k < 5; ++k) {
                    short4v q = *(const short4v*)(pb + 64 * k);
#pragma unroll
                    for (int e = 0; e < 4; ++e) {
                        float v = pav[k][e] + bf2f(q[e]) + b1v[k][e];
                        s += fmaxf(v, 0.f) * w2v[k][e];
                    }
                }
                s += __shfl_down(s, 8, 16); s += __shfl_down(s, 4, 16);
                s += __shfl_down(s, 2, 16); s += __shfl_down(s, 1, 16);
                a = sigf(s + b2v);
            } else {
                a = c0;
            }
            if (c16 == 0) {
                att_out[((size_t)(b * 32 + grp)) * 32 + j] = a;
                attL[grp * 40 + j] = f2bf((j < nr) ? a : 0.f);
            }
        }
    }
    __syncthreads();

    // ---- two message-passing rounds ----
    for (int rnd = 0; rnd < 2; ++rnd) {
        short* src = rnd ? bufB : bufA;
        short* dst = rnd ? bufA : bufB;

        // msg = h @ Wmsg^T + msg_b -> msgT bf16 (round 0 done in P1)
        if (rnd) {
            int s = wave;
            const short* bw = Wmsg + s * 9 * 512 + lane * 8;
            short8 wm[9];
#pragma unroll
            for (int kk = 0; kk < 9; ++kk) wm[kk] = *(const short8*)(bw + kk * 512);
            floatx4 acc0 = {}, acc1 = {};
            const short* ap = src + lrow * KA_S + 128 + quad * 8;
#pragma unroll
            for (int kk = 0; kk < 9; ++kk) {
                short8 x0 = *(const short8*)(ap + kk * 32);
                short8 x1 = *(const short8*)(ap + 16 * KA_S + kk * 32);
                acc0 = MFMA(x0, wm[kk], acc0, 0, 0, 0);
                acc1 = MFMA(x1, wm[kk], acc1, 0, 0, 0);
            }
            int col = s * 16 + lrow;
            float bias = msg_bg[col];
#pragma unroll
            for (int rr = 0; rr < 4; ++rr) {
                msgT[col * 40 + quad * 4 + rr] = f2bf(acc0[rr] + bias);
                msgT[col * 40 + 16 + quad * 4 + rr] = f2bf(acc1[rr] + bias);
            }
            __syncthreads();
        }

        // mix via MFMA: mv = attL(32x32) @ msg -> bf16 src cols 0..127
        {
            int mi = wave & 1, ng = wave >> 1;
            short8 afrag = *(const short8*)(attL + (mi * 16 + lrow) * 40 + quad * 8);
            floatx4 acc0 = {}, acc1 = {};
            short8 bf0 = *(const short8*)(msgT + (ng * 32 + lrow) * 40 + quad * 8);
            short8 bf1 = *(const short8*)(msgT + (ng * 32 + 16 + lrow) * 40 + quad * 8);
            acc0 = MFMA(afrag, bf0, acc0, 0, 0, 0);
            acc1 = MFMA(afrag, bf1, acc1, 0, 0, 0);
#pragma unroll
            for (int rr = 0; rr < 4; ++rr) {
                int m = mi * 16 + quad * 4 + rr;
                src[m * KA_S + ng * 32 + lrow] = f2bf(acc0[rr]);
                src[m * KA_S + ng * 32 + 16 + lrow] = f2bf(acc1[rr]);
            }
        }
        __syncthreads();

        // GRU: tiles 0..15 = exactly 2/wave; tile 16 as m-halves on waves 0/1
        // (per-branch macro: static indexing, no select, no unroll).
        {
            short8 aA0[13], aA1[13];
            {
                const short* ap0 = src + lrow * KA_S + quad * 8;
#pragma unroll
                for (int kk = 0; kk < 13; ++kk) {
                    aA0[kk] = *(const short8*)(ap0 + kk * 32);
                    aA1[kk] = *(const short8*)(ap0 + 16 * KA_S + kk * 32);
                }
#pragma unroll
                for (int kk = 0; kk < 13; ++kk)
                    asm volatile("" : "+v"(aA0[kk]), "+v"(aA1[kk]));
            }
            for (int s = wave; s < 16; s += 8) {
                const short* bpr = Wrz + (s * 13) * 512 + lane * 8;
                const short* bpz = Wrz + (221 + s * 13) * 512 + lane * 8;
                const short* bpx = Wxn + (s * 4) * 512 + lane * 8;
                const short* bph = Whn + (s * 9) * 512 + lane * 8;

                short8 wr[13];
#pragma unroll
                for (int kk = 0; kk < 13; ++kk) wr[kk] = *(const short8*)(bpr + kk * 512);
#pragma unroll
                for (int kk = 0; kk < 13; ++kk) asm volatile("" : "+v"(wr[kk]));

                floatx4 aR0 = {}, aR1 = {}, aZ0 = {}, aZ1 = {};
                floatx4 aN0 = {}, aN1 = {}, aH0 = {}, aH1 = {};
#pragma unroll
                for (int kk = 0; kk < 13; ++kk) {           // r (+x inline); stage z
                    aR0 = MFMA(aA0[kk], wr[kk], aR0, 0, 0, 0);
                    aR1 = MFMA(aA1[kk], wr[kk], aR1, 0, 0, 0);
                    if (kk < 4) {
                        short8 bx = *(const short8*)(bpx + kk * 512);
                        aN0 = MFMA(aA0[kk], bx, aN0, 0, 0, 0);
                        aN1 = MFMA(aA1[kk], bx, aN1, 0, 0, 0);
                    }
                    wr[kk] = *(const short8*)(bpz + kk * 512);
                }
#pragma unroll
                for (int kk = 0; kk < 13; ++kk) {           // z chain; stage h
                    aZ0 = MFMA(aA0[kk], wr[kk], aZ0, 0, 0, 0);
                    aZ1 = MFMA(aA1[kk], wr[kk], aZ1, 0, 0, 0);
                    if (kk < 9) wr[kk] = *(const short8*)(bph + kk * 512);
                }
#pragma unroll
                for (int kk = 0; kk < 9; ++kk) {            // h chain
                    aH0 = MFMA(aA0[kk + 4], wr[kk], aH0, 0, 0, 0);
                    aH1 = MFMA(aA1[kk + 4], wr[kk], aH1, 0, 0, 0);
                }

                const int d = s * 16 + lrow;                // s<=15 -> d<=255 < D
                float bgr = gb[d], bgz = gb[272 + d];
                float bxv = gb[544 + d], bhv = gb[816 + d];
#pragma unroll
                for (int i = 0; i < 2; ++i) {
                    floatx4 vR = i ? aR1 : aR0, vZ = i ? aZ1 : aZ0;
                    floatx4 vN = i ? aN1 : aN0, vH = i ? aH1 : aH0;
#pragma unroll
                    for (int rr = 0; rr < 4; ++rr) {
                        int m = i * 16 + quad * 4 + rr;
                        float rg = sigf(vR[rr] + bgr);
                        float zg = sigf(vZ[rr] + bgz);
                        float cg = tanh_fast(vN[rr] + bxv + rg * (vH[rr] + bhv));
                        float hold = bf2f(src[m * KA_S + 128 + d]);
                        float hv = (1.f - zg) * cg + zg * hold;
                        if (m >= nr) hv = 0.f;
                        dst[m * KA_S + 128 + d] = f2bf(hv);
                    }
                }
            }

            // tail: tile 16 (d 256..261), wave 0 -> rows 0..15 (aA0),
            // wave 1 -> rows 16..31 (aA1). Macro per branch: static indexing.
#define GRU_TAIL(AARR, MB) do { \
            const short* bpr_ = Wrz + (16 * 13) * 512 + lane * 8; \
            const short* bpz_ = Wrz + (221 + 16 * 13) * 512 + lane * 8; \
            const short* bpx_ = Wxn + (16 * 4) * 512 + lane * 8; \
            const short* bph_ = Whn + (16 * 9) * 512 + lane * 8; \
            floatx4 aR_ = {}, aZ_ = {}, aN_ = {}, aH_ = {}; \
            _Pragma("unroll") \
            for (int kk = 0; kk < 13; ++kk) { \
                short8 br_ = *(const short8*)(bpr_ + kk * 512); \
                short8 bz_ = *(const short8*)(bpz_ + kk * 512); \
                aR_ = MFMA(AARR[kk], br_, aR_, 0, 0, 0); \
                aZ_ = MFMA(AARR[kk], bz_, aZ_, 0, 0, 0); \
                if (kk < 4) { \
                    short8 bx_ = *(const short8*)(bpx_ + kk * 512); \
                    aN_ = MFMA(AARR[kk], bx_, aN_, 0, 0, 0); \
                } else { \
                    short8 bh_ = *(const short8*)(bph_ + (kk - 4) * 512); \
                    aH_ = MFMA(AARR[kk], bh_, aH_, 0, 0, 0); \
                } \
            } \
            const int d_ = 256 + lrow; \
            if (d_ < D) { \
                float bgr_ = gb[d_], bgz_ = gb[272 + d_]; \
                float bxv_ = gb[544 + d_], bhv_ = gb[816 + d_]; \
                _Pragma("unroll") \
                for (int rr = 0; rr < 4; ++rr) { \
                    int m_ = (MB) + quad * 4 + rr; \
                    float rg_ = sigf(aR_[rr] + bgr_); \
                    float zg_ = sigf(aZ_[rr] + bgz_); \
                    float cg_ = tanh_fast(aN_[rr] + bxv_ + rg_ * (aH_[rr] + bhv_)); \
                    float hold_ = bf2f(src[m_ * KA_S + 128 + d_]); \
                    float hv_ = (1.f - zg_) * cg_ + zg_ * hold_; \
                    if (m_ >= nr) hv_ = 0.f; \
                    dst[m_ * KA_S + 128 + d_] = f2bf(hv_); \
                } \
            } \
        } while (0)

            if (wave == 0)      GRU_TAIL(aA0, 0);
            else if (wave == 1) GRU_TAIL(aA1, 16);
#undef GRU_TAIL
        }
        __syncthreads();
    }

    // ---- readout: hid = relu(h2 @ Wro^T + ro_b1), h2 in bufA ----
    {
        int s = wave;
        const short* bw = Wro + s * 9 * 512 + lane * 8;
        short8 wv[9];
#pragma unroll
        for (int kk = 0; kk < 9; ++kk) wv[kk] = *(const short8*)(bw + kk * 512);
        floatx4 acc0 = {}, acc1 = {};
        const short* ap = bufA + lrow * KA_S + 128 + quad * 8;
#pragma unroll
        for (int kk = 0; kk < 9; ++kk) {
            short8 x0 = *(const short8*)(ap + kk * 32);
            short8 x1 = *(const short8*)(ap + 16 * KA_S + kk * 32);
            acc0 = MFMA(x0, wv[kk], acc0, 0, 0, 0);
            acc1 = MFMA(x1, wv[kk], acc1, 0, 0, 0);
        }
        int col = s * 16 + lrow;
        float bias = ro_b1g[col];
#pragma unroll
        for (int rr = 0; rr < 4; ++rr) {
            hidL[(quad * 4 + rr) * 136 + col] = f2bf(fmaxf(acc0[rr] + bias, 0.f));
            hidL[(16 + quad * 4 + rr) * 136 + col] = f2bf(fmaxf(acc1[rr] + bias, 0.f));
        }
    }
    __syncthreads();

    // ---- final: pred = hid @ ro_w2^T + ro_b2 (wave 0 only) ----
    if (wave == 0) {
        const short* bw = Wro2 + lane * 8;
        short8 wv[4];
#pragma unroll
        for (int kk = 0; kk < 4; ++kk) wv[kk] = *(const short8*)(bw + kk * 512);
        floatx4 acc0 = {}, acc1 = {};
        const short* ap = hidL + lrow * 136 + quad * 8;
#pragma unroll
        for (int kk = 0; kk < 4; ++kk) {
            short8 x0 = *(const short8*)(ap + kk * 32);
            short8 x1 = *(const short8*)(ap + 16 * 136 + kk * 32);
            acc0 = MFMA(x0, wv[kk], acc0, 0, 0, 0);
            acc1 = MFMA(x1, wv[kk], acc1, 0, 0, 0);
        }
        int q = lrow;
        if (q < NCLS) {
            float bias = ro_b2g[q];
#pragma unroll
            for (int i = 0; i < 2; ++i) {
#pragma unroll
                for (int rr = 0; rr < 4; ++rr) {
                    int m = i * 16 + quad * 4 + rr;
                    float v = (i ? acc1[rr] : acc0[rr]) + bias;
                    if (m >= nr) v = 0.f;
                    pred[((size_t)(b * 32 + m)) * NCLS + q] = v;
                }
            }
        }
    }
}

// ---------------------------------------------------------------------------
extern "C" void kernel_launch(void* const* d_in, const int* in_sizes, int n_in,
                              void* d_out, int out_size, void* d_ws, size_t ws_size,
                              hipStream_t stream)
{
    const float* nodes = (const float*)d_in[0];
    const float* pos   = (const float*)d_in[1];
    const int*   nrec  = (const int*)d_in[2];
    const float* w1    = (const float*)d_in[3];
    const float* b1    = (const float*)d_in[4];
    const float* w2    = (const float*)d_in[5];
    const float* b2    = (const float*)d_in[6];
    const float* msg_w = (const float*)d_in[7];
    const float* msg_b = (const float*)d_in[8];
    const float* w_ih  = (const float*)d_in[9];
    const float* w_hh  = (const float*)d_in[10];
    const float* b_ih  = (const float*)d_in[11];
    const float* b_hh  = (const float*)d_in[12];
    const float* ro_w1 = (const float*)d_in[13];
    const float* ro_b1 = (const float*)d_in[14];
    const float* ro_w2 = (const float*)d_in[15];
    const float* ro_b2 = (const float*)d_in[16];
    float* ws   = (float*)d_ws;
    float* pred = (float*)d_out;
    float* attout = pred + (size_t)N_G * M_N * NCLS;

    prep_kernel<<<278, 256, 0, stream>>>(w1, msg_w, w_ih, w_hh, ro_w1, ro_w2,
                                         b_ih, b_hh, ws);
    fused_kernel<<<N_G, 512, 0, stream>>>(nodes, pos, nrec, b1, w2, b2, msg_b,
                                          ro_b1, ro_b2, ws, attout, pred);
}

// Round 16
// 137.207 us; speedup vs baseline: 1.0734x; 1.0734x over previous
//
#include <hip/hip_runtime.h>
#include <math.h>

#define N_G   64
#define M_N   32
#define FEAT  256
#define POSD  6
#define D     262
#define MSG   128
#define NCLS  7

#define KA_S  424       // LDS buf row stride (shorts): [mv 128 | h 262 | pad]
#define PSTR  320       // paL/pbL row stride (shorts)

// ---------------------------------------------------------------------------
// COALESCED tile-major weight layout (R11). Slab = 512 shorts (64 lanes x 8).
// Chunk (tile s, k-step kk, lane) contiguous -> each wave weight load is one
// 1KB fully-coalesced transaction. Region slab counts:
//   proj 33x9 | msg 8x9 | rz 2x17x13 | xn 17x4 | hn 17x9 | ro 8x9 | ro2 1x4
// NOTE (R13/R15 lesson): this kernel's GRU consumes its register budget
// exactly ({2x13 pinned A + 13 pinned wr + 8 accs}); ANY additional
// concurrent live set (unrolled s-loop, cross-array select, balance tails)
// spills 8-28 MB of scratch and regresses 20-90%. Do not extend live ranges.
// ---------------------------------------------------------------------------
#define O_WPROJ 0u
#define O_WMSG  76032u
#define O_WRZ   94464u
#define O_WXN   207616u
#define O_WHN   225024u
#define O_WRO   264192u
#define O_WRO2  282624u
#define O_GB    283648u   // 1088 fp32 gate biases [br|bz|bxn|bhn] x 272

typedef __attribute__((ext_vector_type(8))) short short8;
typedef __attribute__((ext_vector_type(4))) short short4v;
typedef __attribute__((ext_vector_type(4))) float floatx4;

#define MFMA __builtin_amdgcn_mfma_f32_16x16x32_bf16

__device__ __forceinline__ short f2bf(float f) {
    union { float f; unsigned u; } v; v.f = f;
    unsigned r = v.u + 0x7FFF + ((v.u >> 16) & 1);   // RNE
    return (short)(r >> 16);
}
__device__ __forceinline__ float bf2f(short s) {
    union { float f; unsigned u; } v;
    v.u = ((unsigned)(unsigned short)s) << 16;
    return v.f;
}
// fast sigmoid/tanh: v_exp_f32 + v_rcp_f32 (~1e-6 rel err, vs bf16-path 5e-3)
__device__ __forceinline__ float sigf(float x) {
    return __builtin_amdgcn_rcpf(1.f + __expf(-x));
}
__device__ __forceinline__ float tanh_fast(float x) {
    float e = __expf(-2.f * fabsf(x));
    float t = (1.f - e) * __builtin_amdgcn_rcpf(1.f + e);
    return copysignf(t, x);
}

// ---------------------------------------------------------------------------
// prep: SLAB-PER-WAVE pack into the coalesced tile-major layout (R11).
// ---------------------------------------------------------------------------
__global__ __launch_bounds__(256) void prep_kernel(
    const float* __restrict__ w1, const float* __restrict__ msg_w,
    const float* __restrict__ w_ih, const float* __restrict__ w_hh,
    const float* __restrict__ ro_w1, const float* __restrict__ ro_w2,
    const float* __restrict__ b_ih, const float* __restrict__ b_hh,
    float* __restrict__ ws)
{
    short* wproj = (short*)(ws + O_WPROJ);
    short* wmsg  = (short*)(ws + O_WMSG);
    short* wrz   = (short*)(ws + O_WRZ);
    short* wxn   = (short*)(ws + O_WXN);
    short* whn   = (short*)(ws + O_WHN);
    short* wro   = (short*)(ws + O_WRO);
    short* wro2  = (short*)(ws + O_WRO2);
    float* gb    = ws + O_GB;

    int job = blockIdx.x * 4 + (threadIdx.x >> 6);
    const int lane = threadIdx.x & 63;
    if (job >= 1112) return;
    const int lrow = lane & 15, quad = lane >> 4;

    if (job < 297) {                              // proj: s 0..32, kk 0..8
        const int s = job / 9, kk = job % 9;
        const int n = s * 16 + lrow, kb = quad * 8 + kk * 32;
        short8 o;
#pragma unroll
        for (int e = 0; e < 8; ++e) {
            int k = kb + e;
            float v = 0.f;
            if (k < D && n < 524)
                v = (n < D) ? w1[n * 524 + k] : w1[(n - D) * 524 + D + k];
            o[e] = f2bf(v);
        }
        *(short8*)(wproj + job * 512 + lane * 8) = o;
        return;
    }
    job -= 297;
    if (job < 72) {                               // msg: s 0..7, kk 0..8
        const int s = job / 9, kk = job % 9;
        const int n = s * 16 + lrow, kb = quad * 8 + kk * 32;
        short8 o;
#pragma unroll
        for (int e = 0; e < 8; ++e) {
            int k = kb + e;
            o[e] = f2bf(k < D ? msg_w[n * D + k] : 0.f);
        }
        *(short8*)(wmsg + job * 512 + lane * 8) = o;
        return;
    }
    job -= 72;
    if (job < 442) {                              // rz: [r slabs 0..220][z 221..441]
        const int gi = job >= 221;
        const int jj = job - gi * 221;
        const int s = jj / 13, kk = jj % 13;
        const int d = s * 16 + lrow, kb = quad * 8 + kk * 32;
        short8 o;
#pragma unroll
        for (int e = 0; e < 8; ++e) {
            int k = kb + e;
            float v = 0.f;
            if (d < D) {
                int r = gi * D + d;
                if (k < 128)          v = w_ih[r * MSG + k];
                else if (k < 128 + D) v = w_hh[r * D + (k - 128)];
            }
            o[e] = f2bf(v);
        }
        *(short8*)(wrz + job * 512 + lane * 8) = o;
        return;
    }
    job -= 442;
    if (job < 68) {                               // xn: s 0..16, kk 0..3
        const int s = job / 4, kk = job % 4;
        const int d = s * 16 + lrow, kb = quad * 8 + kk * 32;
        short8 o;
#pragma unroll
        for (int e = 0; e < 8; ++e) {
            int k = kb + e;
            o[e] = f2bf(d < D ? w_ih[(2 * D + d) * MSG + k] : 0.f);
        }
        *(short8*)(wxn + job * 512 + lane * 8) = o;
        return;
    }
    job -= 68;
    if (job < 153) {                              // hn: s 0..16, kk 0..8
        const int s = job / 9, kk = job % 9;
        const int d = s * 16 + lrow, kb = quad * 8 + kk * 32;
        short8 o;
#pragma unroll
        for (int e = 0; e < 8; ++e) {
            int k = kb + e;
            o[e] = f2bf((d < D && k < D) ? w_hh[(2 * D + d) * D + k] : 0.f);
        }
        *(short8*)(whn + job * 512 + lane * 8) = o;
        return;
    }
    job -= 153;
    if (job < 72) {                               // ro: s 0..7, kk 0..8
        const int s = job / 9, kk = job % 9;
        const int n = s * 16 + lrow, kb = quad * 8 + kk * 32;
        short8 o;
#pragma unroll
        for (int e = 0; e < 8; ++e) {
            int k = kb + e;
            o[e] = f2bf(k < D ? ro_w1[n * D + k] : 0.f);
        }
        *(short8*)(wro + job * 512 + lane * 8) = o;
        return;
    }
    job -= 72;
    if (job < 4) {                                // ro2: kk 0..3
        const int kk = job;
        const int n = lrow, kb = quad * 8 + kk * 32;
        short8 o;
#pragma unroll
        for (int e = 0; e < 8; ++e) {
            int k = kb + e;
            o[e] = f2bf(n < NCLS ? ro_w2[n * MSG + k] : 0.f);
        }
        *(short8*)(wro2 + job * 512 + lane * 8) = o;
        return;
    }
    job -= 4;
    {                                             // gate biases [4][272]
        const int seg = job;
        float* out = gb + seg * 272;
        for (int d = lane; d < 272; d += 64) {
            float v = 0.f;
            if (d < D) {
                if (seg == 0)      v = b_ih[d] + b_hh[d];
                else if (seg == 1) v = b_ih[D + d] + b_hh[D + d];
                else if (seg == 2) v = b_ih[2 * D + d];
                else               v = b_hh[2 * D + d];
            }
            out[d] = v;
        }
    }
}

// ---------------------------------------------------------------------------
// fused: one block per graph; FINAL = R11/R14 configuration (best measured:
// 49.1-49.5us fused, 137.4us total). 512 threads, coalesced slab weight
// loads, pinned A-fragments, runtime GRU s-loop, no cross-array selects.
// ---------------------------------------------------------------------------
__global__ __launch_bounds__(512, 2) void fused_kernel(
    const float* __restrict__ nodes, const float* __restrict__ pos,
    const int* __restrict__ nrec_g,
    const float* __restrict__ b1g, const float* __restrict__ w2g,
    const float* __restrict__ b2g, const float* __restrict__ msg_bg,
    const float* __restrict__ ro_b1g, const float* __restrict__ ro_b2g,
    const float* __restrict__ ws,
    float* __restrict__ att_out, float* __restrict__ pred)
{
    const short* Wproj = (const short*)(ws + O_WPROJ);
    const short* Wmsg  = (const short*)(ws + O_WMSG);
    const short* Wrz   = (const short*)(ws + O_WRZ);
    const short* Wxn   = (const short*)(ws + O_WXN);
    const short* Whn   = (const short*)(ws + O_WHN);
    const short* Wro   = (const short*)(ws + O_WRO);
    const short* Wro2  = (const short*)(ws + O_WRO2);
    const float* gb    = ws + O_GB;

    __shared__ __align__(16) short bufA[32 * KA_S];
    __shared__ __align__(16) short bufB[32 * KA_S];
    __shared__ __align__(16) short paL[32 * PSTR];
    __shared__ __align__(16) short pbL[32 * PSTR];
    __shared__ __align__(16) short attL[32 * 40];   // bf16 A-layout for mix
    __shared__ __align__(16) short msgT[128 * 40];  // bf16 B^T layout for mix
    __shared__ __align__(16) short hidL[32 * 136];
    __shared__ __align__(16) float b1L[PSTR], w2L[PSTR];

    const int b = blockIdx.x;
    const int tid = threadIdx.x;
    const int wave = tid >> 6, lane = tid & 63;
    const int quad = lane >> 4, lrow = lane & 15;

    // ---- L2 priming: touch Wrz/Wxn/Whn (contiguous ~679 KB) early ----
    floatx4 prm[10];
    {
        const floatx4* pb = (const floatx4*)(ws + O_WRZ);
        const int base = wave * 64 + lane;
#pragma unroll
        for (int p = 0; p < 10; ++p)
            prm[p] = pb[(p * 512 + base) * 8];      // 8 floatx4 = 128 B stride
    }
    // ---- prefetch P1 tile-'wave' weights (hides under P0) ----
    short8 wvA[9];
    {
        const short* bw = Wproj + wave * 9 * 512 + lane * 8;
#pragma unroll
        for (int kk = 0; kk < 9; ++kk) wvA[kk] = *(const short8*)(bw + kk * 512);
    }

    const int nr = nrec_g[b];

    // ---- P0: load h0 bf16, zero pads, stage padded b1/w2 ----
    for (int idx = tid; idx < 32 * 64; idx += 512) {          // nodes (float4)
        int w = idx >> 6, c4 = idx & 63;
        floatx4 v = *(const floatx4*)(nodes + ((size_t)(b * 32 + w)) * FEAT + c4 * 4);
        short4v s; s[0] = f2bf(v[0]); s[1] = f2bf(v[1]); s[2] = f2bf(v[2]); s[3] = f2bf(v[3]);
        *(short4v*)(bufA + w * KA_S + 128 + c4 * 4) = s;
    }
    for (int idx = tid; idx < 32 * POSD; idx += 512) {        // pos
        int w = idx / POSD, c = idx % POSD;
        bufA[w * KA_S + 128 + FEAT + c] = f2bf(pos[((size_t)(b * 32 + w)) * POSD + c]);
    }
    for (int idx = tid; idx < 32 * 34; idx += 512) {          // col pads 390..423
        int w = idx / 34, c = idx % 34;
        bufA[w * KA_S + 390 + c] = 0;
        bufB[w * KA_S + 390 + c] = 0;
    }
    for (int idx = tid; idx < 32 * (PSTR - D); idx += 512) {  // pa/pb pads 262..319
        int w = idx / (PSTR - D), c = idx % (PSTR - D);
        paL[w * PSTR + D + c] = 0;
        pbL[w * PSTR + D + c] = 0;
    }
    for (int d = tid; d < PSTR; d += 512) {
        b1L[d] = (d < D) ? b1g[d] : 0.f;
        w2L[d] = (d < D) ? w2g[d] : 0.f;
    }
    // keep priming loads alive (and let their latency overlap P0's work)
#pragma unroll
    for (int p = 0; p < 10; ++p) asm volatile("" :: "v"(prm[p]));
    __syncthreads();

    // ---- P1: combined GEMM over h0 (tiles 0..32 proj, 33..40 round-0 msg) ----
    {
        auto store_proj = [&](int s, floatx4 acc0, floatx4 acc1) {
            int col = s * 16 + lrow;
#pragma unroll
            for (int rr = 0; rr < 4; ++rr) {
                int r0 = quad * 4 + rr;
                if (col < D) {
                    paL[r0 * PSTR + col] = f2bf(acc0[rr]);
                    paL[(r0 + 16) * PSTR + col] = f2bf(acc1[rr]);
                } else if (col < 2 * D) {
                    pbL[r0 * PSTR + (col - D)] = f2bf(acc0[rr]);
                    pbL[(r0 + 16) * PSTR + (col - D)] = f2bf(acc1[rr]);
                }
            }
        };
        auto store_msg = [&](int s, floatx4 acc0, floatx4 acc1) {
            int col = (s - 33) * 16 + lrow;
            float bias = msg_bg[col];
#pragma unroll
            for (int rr = 0; rr < 4; ++rr) {
                msgT[col * 40 + quad * 4 + rr] = f2bf(acc0[rr] + bias);
                msgT[col * 40 + 16 + quad * 4 + rr] = f2bf(acc1[rr] + bias);
            }
        };

        short8 aF0[9], aF1[9];
        {
            const short* ap = bufA + lrow * KA_S + 128 + quad * 8;
#pragma unroll
            for (int kk = 0; kk < 9; ++kk) {
                aF0[kk] = *(const short8*)(ap + kk * 32);
                aF1[kk] = *(const short8*)(ap + 16 * KA_S + kk * 32);
            }
#pragma unroll
            for (int kk = 0; kk < 9; ++kk)
                asm volatile("" : "+v"(aF0[kk]), "+v"(aF1[kk]));
        }
        short8 wvB[9];

#define P1_LOAD(DST, TT) do { \
            const short* bw_ = ((TT) < 33) \
                ? Wproj + (TT) * 9 * 512 + lane * 8 \
                : Wmsg + ((TT) - 33) * 9 * 512 + lane * 8; \
            _Pragma("unroll") \
            for (int kk = 0; kk < 9; ++kk) DST[kk] = *(const short8*)(bw_ + kk * 512); \
        } while (0)

#define P1_TILE(W, TT) do { \
            floatx4 acc0_ = {}, acc1_ = {}; \
            _Pragma("unroll") \
            for (int kk = 0; kk < 9; ++kk) { \
                acc0_ = MFMA(aF0[kk], W[kk], acc0_, 0, 0, 0); \
                acc1_ = MFMA(aF1[kk], W[kk], acc1_, 0, 0, 0); \
            } \
            if ((TT) < 33) store_proj((TT), acc0_, acc1_); \
            else store_msg((TT), acc0_, acc1_); \
        } while (0)

        int t = wave;                       // 0..7
        P1_LOAD(wvB, t + 8);                // stage next while computing current
        P1_TILE(wvA, t);
        t += 8;                             // 8..15
        P1_LOAD(wvA, t + 8);
        P1_TILE(wvB, t);
        t += 8;                             // 16..23
        P1_LOAD(wvB, t + 8);
        P1_TILE(wvA, t);
        t += 8;                             // 24..31
        P1_LOAD(wvA, t + 8);                // 32..39: always valid
        P1_TILE(wvB, t);
        t += 8;                             // 32..39
        if (t + 8 < 41) P1_LOAD(wvB, t + 8);  // only wave 0 stages tile 40
        P1_TILE(wvA, t);
        t += 8;                             // 40 for wave 0
        if (t < 41) P1_TILE(wvB, t);
#undef P1_LOAD
#undef P1_TILE
    }
    __syncthreads();

    // ---- P2: attention — 32 groups of 16 lanes, 32 j's each ----
    {
        const int grp = tid >> 4;          // i = grp (0..31)
        const int c16 = tid & 15;
        const float b2v = b2g[0];
        float pav[5][4], b1v[5][4], w2v[5][4];
#pragma unroll
        for (int k = 0; k < 5; ++k) {
            int dbase = c16 * 4 + 64 * k;
            short4v p = *(const short4v*)(paL + grp * PSTR + dbase);
            floatx4 bb = *(const floatx4*)(b1L + dbase);
            floatx4 ww = *(const floatx4*)(w2L + dbase);
#pragma unroll
            for (int e = 0; e < 4; ++e) {
                pav[k][e] = bf2f(p[e]); b1v[k][e] = bb[e]; w2v[k][e] = ww[e];
            }
        }
        // c0 = invalid-pair logit
        float p0 = 0.f;
#pragma unroll
        for (int k = 0; k < 5; ++k)
#pragma unroll
            for (int e = 0; e < 4; ++e)
                p0 += fmaxf(b1v[k][e], 0.f) * w2v[k][e];
        p0 += __shfl_down(p0, 8, 16); p0 += __shfl_down(p0, 4, 16);
        p0 += __shfl_down(p0, 2, 16); p0 += __shfl_down(p0, 1, 16);
        float c0 = sigf(p0 + b2v);
        const bool vi = grp < nr;
        for (int j = 0; j < 32; ++j) {
            float a;
            if (j < nr && vi) {
                const short* pb = pbL + j * PSTR + c16 * 4;
                float s = 0.f;
#pragma unroll
                for (int k = 0; k < 5; ++k) {
                    short4v q = *(const short4v*)(pb + 64 * k);
#pragma unroll
                    for (int e = 0; e < 4; ++e) {
                        float v = pav[k][e] + bf2f(q[e]) + b1v[k][e];
                        s += fmaxf(v, 0.f) * w2v[k][e];
                    }
                }
                s += __shfl_down(s, 8, 16); s += __shfl_down(s, 4, 16);
                s += __shfl_down(s, 2, 16); s += __shfl_down(s, 1, 16);
                a = sigf(s + b2v);
            } else {
                a = c0;
            }
            if (c16 == 0) {
                att_out[((size_t)(b * 32 + grp)) * 32 + j] = a;
                attL[grp * 40 + j] = f2bf((j < nr) ? a : 0.f);
            }
        }
    }
    __syncthreads();

    // ---- two message-passing rounds ----
    for (int rnd = 0; rnd < 2; ++rnd) {
        short* src = rnd ? bufB : bufA;
        short* dst = rnd ? bufA : bufB;

        // msg = h @ Wmsg^T + msg_b -> msgT bf16 (round 0 done in P1)
        if (rnd) {
            int s = wave;
            const short* bw = Wmsg + s * 9 * 512 + lane * 8;
            short8 wm[9];
#pragma unroll
            for (int kk = 0; kk < 9; ++kk) wm[kk] = *(const short8*)(bw + kk * 512);
            floatx4 acc0 = {}, acc1 = {};
            const short* ap = src + lrow * KA_S + 128 + quad * 8;
#pragma unroll
            for (int kk = 0; kk < 9; ++kk) {
                short8 x0 = *(const short8*)(ap + kk * 32);
                short8 x1 = *(const short8*)(ap + 16 * KA_S + kk * 32);
                acc0 = MFMA(x0, wm[kk], acc0, 0, 0, 0);
                acc1 = MFMA(x1, wm[kk], acc1, 0, 0, 0);
            }
            int col = s * 16 + lrow;
            float bias = msg_bg[col];
#pragma unroll
            for (int rr = 0; rr < 4; ++rr) {
                msgT[col * 40 + quad * 4 + rr] = f2bf(acc0[rr] + bias);
                msgT[col * 40 + 16 + quad * 4 + rr] = f2bf(acc1[rr] + bias);
            }
            __syncthreads();
        }

        // mix via MFMA: mv = attL(32x32) @ msg -> bf16 src cols 0..127
        {
            int mi = wave & 1, ng = wave >> 1;
            short8 afrag = *(const short8*)(attL + (mi * 16 + lrow) * 40 + quad * 8);
            floatx4 acc0 = {}, acc1 = {};
            short8 bf0 = *(const short8*)(msgT + (ng * 32 + lrow) * 40 + quad * 8);
            short8 bf1 = *(const short8*)(msgT + (ng * 32 + 16 + lrow) * 40 + quad * 8);
            acc0 = MFMA(afrag, bf0, acc0, 0, 0, 0);
            acc1 = MFMA(afrag, bf1, acc1, 0, 0, 0);
#pragma unroll
            for (int rr = 0; rr < 4; ++rr) {
                int m = mi * 16 + quad * 4 + rr;
                src[m * KA_S + ng * 32 + lrow] = f2bf(acc0[rr]);
                src[m * KA_S + ng * 32 + 16 + lrow] = f2bf(acc1[rr]);
            }
        }
        __syncthreads();

        // GRU: fused [gx|gh] GEMM + elementwise, writes dst h-cols.
        // Weight loads fully coalesced: chunk (s,kk,lane) contiguous.
        {
            short8 aA0[13], aA1[13];
            {
                const short* ap0 = src + lrow * KA_S + quad * 8;
#pragma unroll
                for (int kk = 0; kk < 13; ++kk) {
                    aA0[kk] = *(const short8*)(ap0 + kk * 32);
                    aA1[kk] = *(const short8*)(ap0 + 16 * KA_S + kk * 32);
                }
#pragma unroll
                for (int kk = 0; kk < 13; ++kk)
                    asm volatile("" : "+v"(aA0[kk]), "+v"(aA1[kk]));
            }
            for (int s = wave; s < 17; s += 8) {
                const short* bpr = Wrz + (s * 13) * 512 + lane * 8;
                const short* bpz = Wrz + (221 + s * 13) * 512 + lane * 8;
                const short* bpx = Wxn + (s * 4) * 512 + lane * 8;
                const short* bph = Whn + (s * 9) * 512 + lane * 8;

                short8 wr[13];
#pragma unroll
                for (int kk = 0; kk < 13; ++kk) wr[kk] = *(const short8*)(bpr + kk * 512);
#pragma unroll
                for (int kk = 0; kk < 13; ++kk) asm volatile("" : "+v"(wr[kk]));

                floatx4 aR0 = {}, aR1 = {}, aZ0 = {}, aZ1 = {};
                floatx4 aN0 = {}, aN1 = {}, aH0 = {}, aH1 = {};
#pragma unroll
                for (int kk = 0; kk < 13; ++kk) {           // r (+x inline); stage z
                    aR0 = MFMA(aA0[kk], wr[kk], aR0, 0, 0, 0);
                    aR1 = MFMA(aA1[kk], wr[kk], aR1, 0, 0, 0);
                    if (kk < 4) {
                        short8 bx = *(const short8*)(bpx + kk * 512);
                        aN0 = MFMA(aA0[kk], bx, aN0, 0, 0, 0);
                        aN1 = MFMA(aA1[kk], bx, aN1, 0, 0, 0);
                    }
                    wr[kk] = *(const short8*)(bpz + kk * 512);
                }
#pragma unroll
                for (int kk = 0; kk < 13; ++kk) {           // z chain; stage h
                    aZ0 = MFMA(aA0[kk], wr[kk], aZ0, 0, 0, 0);
                    aZ1 = MFMA(aA1[kk], wr[kk], aZ1, 0, 0, 0);
                    if (kk < 9) wr[kk] = *(const short8*)(bph + kk * 512);
                }
#pragma unroll
                for (int kk = 0; kk < 9; ++kk) {            // h chain
                    aH0 = MFMA(aA0[kk + 4], wr[kk], aH0, 0, 0, 0);
                    aH1 = MFMA(aA1[kk + 4], wr[kk], aH1, 0, 0, 0);
                }

                int d = s * 16 + lrow;
                if (d < D) {
                    float bgr = gb[d], bgz = gb[272 + d];
                    float bxv = gb[544 + d], bhv = gb[816 + d];
#pragma unroll
                    for (int i = 0; i < 2; ++i) {
                        floatx4 vR = i ? aR1 : aR0, vZ = i ? aZ1 : aZ0;
                        floatx4 vN = i ? aN1 : aN0, vH = i ? aH1 : aH0;
#pragma unroll
                        for (int rr = 0; rr < 4; ++rr) {
                            int m = i * 16 + quad * 4 + rr;
                            float rg = sigf(vR[rr] + bgr);
                            float zg = sigf(vZ[rr] + bgz);
                            float cg = tanh_fast(vN[rr] + bxv + rg * (vH[rr] + bhv));
                            float hold = bf2f(src[m * KA_S + 128 + d]);
                            float hv = (1.f - zg) * cg + zg * hold;
                            if (m >= nr) hv = 0.f;
                            dst[m * KA_S + 128 + d] = f2bf(hv);
                        }
                    }
                }
            }
        }
        __syncthreads();
    }

    // ---- readout: hid = relu(h2 @ Wro^T + ro_b1), h2 in bufA ----
    {
        int s = wave;
        const short* bw = Wro + s * 9 * 512 + lane * 8;
        short8 wv[9];
#pragma unroll
        for (int kk = 0; kk < 9; ++kk) wv[kk] = *(const short8*)(bw + kk * 512);
        floatx4 acc0 = {}, acc1 = {};
        const short* ap = bufA + lrow * KA_S + 128 + quad * 8;
#pragma unroll
        for (int kk = 0; kk < 9; ++kk) {
            short8 x0 = *(const short8*)(ap + kk * 32);
            short8 x1 = *(const short8*)(ap + 16 * KA_S + kk * 32);
            acc0 = MFMA(x0, wv[kk], acc0, 0, 0, 0);
            acc1 = MFMA(x1, wv[kk], acc1, 0, 0, 0);
        }
        int col = s * 16 + lrow;
        float bias = ro_b1g[col];
#pragma unroll
        for (int rr = 0; rr < 4; ++rr) {
            hidL[(quad * 4 + rr) * 136 + col] = f2bf(fmaxf(acc0[rr] + bias, 0.f));
            hidL[(16 + quad * 4 + rr) * 136 + col] = f2bf(fmaxf(acc1[rr] + bias, 0.f));
        }
    }
    __syncthreads();

    // ---- final: pred = hid @ ro_w2^T + ro_b2 (wave 0 only) ----
    if (wave == 0) {
        const short* bw = Wro2 + lane * 8;
        short8 wv[4];
#pragma unroll
        for (int kk = 0; kk < 4; ++kk) wv[kk] = *(const short8*)(bw + kk * 512);
        floatx4 acc0 = {}, acc1 = {};
        const short* ap = hidL + lrow * 136 + quad * 8;
#pragma unroll
        for (int kk = 0; kk < 4; ++kk) {
            short8 x0 = *(const short8*)(ap + kk * 32);
            short8 x1 = *(const short8*)(ap + 16 * 136 + kk * 32);
            acc0 = MFMA(x0, wv[kk], acc0, 0, 0, 0);
            acc1 = MFMA(x1, wv[kk], acc1, 0, 0, 0);
        }
        int q = lrow;
        if (q < NCLS) {
            float bias = ro_b2g[q];
#pragma unroll
            for (int i = 0; i < 2; ++i) {
#pragma unroll
                for (int rr = 0; rr < 4; ++rr) {
                    int m = i * 16 + quad * 4 + rr;
                    float v = (i ? acc1[rr] : acc0[rr]) + bias;
                    if (m >= nr) v = 0.f;
                    pred[((size_t)(b * 32 + m)) * NCLS + q] = v;
                }
            }
        }
    }
}

// ---------------------------------------------------------------------------
extern "C" void kernel_launch(void* const* d_in, const int* in_sizes, int n_in,
                              void* d_out, int out_size, void* d_ws, size_t ws_size,
                              hipStream_t stream)
{
    const float* nodes = (const float*)d_in[0];
    const float* pos   = (const float*)d_in[1];
    const int*   nrec  = (const int*)d_in[2];
    const float* w1    = (const float*)d_in[3];
    const float* b1    = (const float*)d_in[4];
    const float* w2    = (const float*)d_in[5];
    const float* b2    = (const float*)d_in[6];
    const float* msg_w = (const float*)d_in[7];
    const float* msg_b = (const float*)d_in[8];
    const float* w_ih  = (const float*)d_in[9];
    const float* w_hh  = (const float*)d_in[10];
    const float* b_ih  = (const float*)d_in[11];
    const float* b_hh  = (const float*)d_in[12];
    const float* ro_w1 = (const float*)d_in[13];
    const float* ro_b1 = (const float*)d_in[14];
    const float* ro_w2 = (const float*)d_in[15];
    const float* ro_b2 = (const float*)d_in[16];
    float* ws   = (float*)d_ws;
    float* pred = (float*)d_out;
    float* attout = pred + (size_t)N_G * M_N * NCLS;

    prep_kernel<<<278, 256, 0, stream>>>(w1, msg_w, w_ih, w_hh, ro_w1, ro_w2,
                                         b_ih, b_hh, ws);
    fused_kernel<<<N_G, 512, 0, stream>>>(nodes, pos, nrec, b1, w2, b2, msg_b,
                                          ro_b1, ro_b2, ws, attout, pred);
}